// Round 11
// baseline (55613.696 us; speedup 1.0000x reference)
//
#include <hip/hip_runtime.h>
#include <hip/hip_bf16.h>

// HGT forward, MI355X — ROUND 11: FLOAT32 OUTPUTS (the fix).
// Root cause of rounds 1-10: reference returns float32, so d_out is float*;
// writing bf16 u16-pairs made the harness read decorrelated f32 words
// (absmax ~0.545, insensitive to pipeline structure — exactly as observed).
// Pipeline: round-8 pure-f32 naive kernels. Inputs f32, edges int32 (probed).

#define HH 8
#define HID 128
#define INC 256
#define TTYPES 2

typedef unsigned int u32;

__device__ __forceinline__ float gelu_f(float x) {
    return 0.5f * x * (1.0f + erff(x * 0.7071067811865476f));
}

// ---------------- NAIVE GEMM: one thread per (row, col), all f32 --------------------
// AIN: 0 none, 1 gelu. AOUT: 0 none, 1 relu, 2 skip blend out = g*v + (1-g)*out_old.
template <int CIN, int COUT, int AIN, int AOUT>
__global__ __launch_bounds__(256) void ngemm(
    const float* __restrict__ in, const float* __restrict__ W,
    const float* __restrict__ bias, float* __restrict__ out, int nrows,
    const float* __restrict__ gatep)
{
    int idx = blockIdx.x * 256 + threadIdx.x;
    if (idx >= nrows * COUT) return;
    int n = idx / COUT, j = idx - n * COUT;
    const float* ip = in + (size_t)n * CIN;
    float acc = 0.f;
    for (int c = 0; c < CIN; ++c) {
        float xv = ip[c];
        if (AIN == 1) xv = gelu_f(xv);
        acc += xv * W[(size_t)c * COUT + j];
    }
    float v = acc + bias[j];
    if (AOUT == 1) v = fmaxf(v, 0.f);
    size_t o = (size_t)n * COUT + j;
    if (AOUT == 2) {
        float g = 1.0f / (1.0f + expf(-gatep[0]));
        v = g * v + (1.0f - g) * out[o];
    }
    out[o] = v;
}

// ---- NAIVE relation transform, in-place safe: one thread per (n,h), f32 ------------
// out[n, h*16+e] = sum_d in[n, h*16+d] * rel[h][d][e]
__global__ __launch_bounds__(256) void ntrans(
    const float* in, const float* rel, float* out, int N)
{
    int idx = blockIdx.x * 256 + threadIdx.x;   // n*8 + h
    if (idx >= N * 8) return;
    int n = idx >> 3, h = idx & 7;
    const float* ip = in + (size_t)n * 128 + h * 16;
    float* op = out + (size_t)n * 128 + h * 16;
    float vin[16];
#pragma unroll
    for (int d = 0; d < 16; ++d) vin[d] = ip[d];
    const float* R = rel + h * 256;
    float vout[16];
#pragma unroll
    for (int e = 0; e < 16; ++e) {
        float acc = 0.f;
#pragma unroll
        for (int d = 0; d < 16; ++d) acc += vin[d] * R[d * 16 + e];
        vout[e] = acc;
    }
#pragma unroll
    for (int e = 0; e < 16; ++e) op[e] = vout[e];
}

// ---- per-edge softmax denominator: one thread per (edge, head), f32 ----------------
__global__ __launch_bounds__(256) void epass1_kernel(
    const float* __restrict__ q, const float* __restrict__ kk,
    const int* __restrict__ ei,
    const float* __restrict__ prel, float* __restrict__ ssum, int E)
{
    int i = blockIdx.x * 256 + threadIdx.x;
    if (i >= E * 8) return;
    int e = i >> 3, h = i & 7;
    int s = ei[e], d = ei[E + e];
    const float* qp = q + (size_t)d * 128 + h * 16;
    const float* kp = kk + (size_t)s * 128 + h * 16;
    float acc = 0.f;
#pragma unroll
    for (int j = 0; j < 16; ++j) acc += qp[j] * kp[j];
    float sarg = fminf(fmaxf(acc * prel[h] * 0.25f, -60.f), 60.f);
    atomicAdd(&ssum[(size_t)d * 8 + h], expf(sarg));
}

// ---- per-edge weighted message accumulate, f32 -------------------------------------
__global__ __launch_bounds__(256) void epass2_kernel(
    const float* __restrict__ q, const float* __restrict__ kk,
    const float* __restrict__ vv, const int* __restrict__ ei,
    const float* __restrict__ prel, const float* __restrict__ ssum,
    float* __restrict__ agg, int E)
{
    int i = blockIdx.x * 256 + threadIdx.x;
    if (i >= E * 8) return;
    int e = i >> 3, h = i & 7;
    int s = ei[e], d = ei[E + e];
    const float* qp = q + (size_t)d * 128 + h * 16;
    const float* kp = kk + (size_t)s * 128 + h * 16;
    float acc = 0.f;
#pragma unroll
    for (int j = 0; j < 16; ++j) acc += qp[j] * kp[j];
    float sarg = fminf(fmaxf(acc * prel[h] * 0.25f, -60.f), 60.f);
    float alpha = expf(sarg) / (ssum[(size_t)d * 8 + h] + 1e-16f);
    const float* vp = vv + (size_t)s * 128 + h * 16;
    float* ap = agg + (size_t)d * 128 + h * 16;
#pragma unroll
    for (int j = 0; j < 16; ++j) atomicAdd(&ap[j], alpha * vp[j]);
}

// ---------------- NAIVE L2 normalize: one thread per row, f32 -> f32 ----------------
__global__ __launch_bounds__(256) void nnorm(
    const float* __restrict__ h0, float* __restrict__ emb, int N)
{
    int n = blockIdx.x * 256 + threadIdx.x;
    if (n >= N) return;
    const float* ip = h0 + (size_t)n * 128;
    float s = 0.f;
    for (int c = 0; c < 128; ++c) s += ip[c] * ip[c];
    float sc = 1.0f / fmaxf(sqrtf(s), 1e-12f);
    if (!isfinite(sc)) sc = 0.f;
    float* op = emb + (size_t)n * 128;
    for (int c = 0; c < 128; ++c) op[c] = ip[c] * sc;
}

// ---------------- sentinel (f32) ----------------------------------------------------
__global__ void sentinel_kernel(float* out, int n, float val) {
    int i = blockIdx.x * 256 + threadIdx.x;
    if (i < n) out[i] = val;
}

extern "C" void kernel_launch(void* const* d_in, const int* in_sizes, int n_in,
                              void* d_out, int out_size, void* d_ws, size_t ws_size,
                              hipStream_t stream)
{
    const int N = in_sizes[0] / (TTYPES * INC);
    const int E = in_sizes[19] / 2;
    const size_t NH = (size_t)N * HID;

    const size_t need = 6 * NH * 4;   // 153.6 MB (proven available)
    if (ws_size < need) {
        sentinel_kernel<<<(out_size + 255) / 256, 256, 0, stream>>>(
            (float*)d_out, out_size, 30.0f);
        return;
    }

    const float* x     = (const float*)d_in[0];
    const float* encW  = (const float*)d_in[1];
    const float* encb  = (const float*)d_in[2];
    const float* kW    = (const float*)d_in[3];
    const float* kb    = (const float*)d_in[4];
    const float* qW    = (const float*)d_in[5];
    const float* qb    = (const float*)d_in[6];
    const float* vW    = (const float*)d_in[7];
    const float* vb    = (const float*)d_in[8];
    const float* aW    = (const float*)d_in[9];
    const float* ab    = (const float*)d_in[10];
    const float* skipw = (const float*)d_in[11];
    const float* arel  = (const float*)d_in[12];
    const float* mrel  = (const float*)d_in[13];
    const float* prel  = (const float*)d_in[14];
    const float* dW1   = (const float*)d_in[15];
    const float* db1   = (const float*)d_in[16];
    const float* dW2   = (const float*)d_in[17];
    const float* db2   = (const float*)d_in[18];

    // ws layout (all f32): hbuf[2NH] | T1 q | T3 kk | T4 vv | agg0
    float* hbuf = (float*)d_ws;
    float* T1   = hbuf + 2 * NH;
    float* T3   = T1 + NH;
    float* T4   = T3 + NH;
    float* agg0 = T4 + NH;
    // d_out-backed f32 scratch, dead before final emb/rec writes:
    float* agg1 = (float*)d_out;          // [N][128]
    float* ssum = agg1 + NH;              // [N][8]

    static const int st_[4] = {0, 1, 0, 1};
    static const int dt_[4] = {1, 0, 0, 1};
    float* aggs[2] = {agg0, agg1};

    const int G128 = (N * 128 + 255) / 256;
    const int G256 = (N * 256 + 255) / 256;
    const int GT   = (N * 8 + 255) / 256;
    const int EB   = (E * 8 + 255) / 256;

    // encoder: h[t] = relu(x[t] @ encW[t] + encb[t])
    for (int t = 0; t < TTYPES; ++t) {
        ngemm<INC, HID, 0, 1><<<G128, 256, 0, stream>>>(
            x + (size_t)t * N * INC, encW + (size_t)t * INC * HID, encb + t * HID,
            hbuf + t * NH, N, nullptr);
    }

    for (int l = 0; l < 2; ++l) {
        hipMemsetAsync(agg0, 0, NH * 4, stream);
        hipMemsetAsync(agg1, 0, NH * 4, stream);
        for (int et = 0; et < 4; ++et) {
            int st = st_[et], dt = dt_[et];
            int bs = l * 2 + st, bd = l * 2 + dt;
            int rel = l * 4 + et;
            const int* ei = (const int*)d_in[19 + et];
            // q = h[dt] @ qW[bd] + qb[bd]
            ngemm<HID, HID, 0, 0><<<G128, 256, 0, stream>>>(
                hbuf + dt * NH, qW + (size_t)bd * HID * HID, qb + (size_t)bd * HID,
                T1, N, nullptr);
            // kk = (h[st] @ kW[bs] + kb[bs]) @ arel[rel]
            ngemm<HID, HID, 0, 0><<<G128, 256, 0, stream>>>(
                hbuf + st * NH, kW + (size_t)bs * HID * HID, kb + (size_t)bs * HID,
                T3, N, nullptr);
            ntrans<<<GT, 256, 0, stream>>>(T3, arel + (size_t)rel * 2048, T3, N);
            // vv = (h[st] @ vW[bs] + vb[bs]) @ mrel[rel]
            ngemm<HID, HID, 0, 0><<<G128, 256, 0, stream>>>(
                hbuf + st * NH, vW + (size_t)bs * HID * HID, vb + (size_t)bs * HID,
                T4, N, nullptr);
            ntrans<<<GT, 256, 0, stream>>>(T4, mrel + (size_t)rel * 2048, T4, N);
            // per-edge softmax + aggregate
            hipMemsetAsync(ssum, 0, (size_t)N * 8 * 4, stream);
            epass1_kernel<<<EB, 256, 0, stream>>>(
                T1, T3, ei, prel + (size_t)rel * HH, ssum, E);
            epass2_kernel<<<EB, 256, 0, stream>>>(
                T1, T3, T4, ei, prel + (size_t)rel * HH, ssum, aggs[dt], E);
        }
        // h[t] = g*(gelu(agg[t]) @ aW + ab) + (1-g)*h[t]
        for (int t = 0; t < TTYPES; ++t) {
            int b = l * 2 + t;
            ngemm<HID, HID, 1, 2><<<G128, 256, 0, stream>>>(
                aggs[t], aW + (size_t)b * HID * HID, ab + (size_t)b * HID,
                hbuf + t * NH, N, skipw + b);
        }
    }

    float* emb = (float*)d_out;           // [N][128] f32
    float* rec = emb + NH;                // [N][256] f32
    nnorm<<<(N + 255) / 256, 256, 0, stream>>>(hbuf, emb, N);
    ngemm<HID, HID, 0, 1><<<G128, 256, 0, stream>>>(
        hbuf, dW1, db1, agg0, N, nullptr);
    ngemm<HID, INC, 0, 0><<<G256, 256, 0, stream>>>(
        agg0, dW2, db2, rec, N, nullptr);
}

// Round 12
// 7494.913 us; speedup vs baseline: 7.4202x; 7.4202x over previous
//
#include <hip/hip_runtime.h>
#include <hip/hip_bf16.h>

// HGT forward, MI355X — ROUND 12: CSR-gather attention (no atomics), folded arel,
// post-aggregation mrel. Pure f32 (r11-verified math), f32 outputs.
// ws = 6*NH*4 = 153.6 MB (proven). CSR + qWA live in d_out's rec region
// (dead until the final decoder GEMM); agg1 lives in d_out's emb region
// (dead before nnorm writes emb).

#define HH 8
#define HID 128
#define INC 256
#define TTYPES 2

typedef unsigned int u32;

__device__ __forceinline__ float gelu_f(float x) {
    return 0.5f * x * (1.0f + erff(x * 0.7071067811865476f));
}

// ---------------- NAIVE GEMM: one thread per (row, col), all f32 --------------------
// AIN: 0 none, 1 gelu. AOUT: 0 none, 1 relu, 2 skip blend out = g*v + (1-g)*out_old.
template <int CIN, int COUT, int AIN, int AOUT>
__global__ __launch_bounds__(256) void ngemm(
    const float* __restrict__ in, const float* __restrict__ W,
    const float* __restrict__ bias, float* __restrict__ out, int nrows,
    const float* __restrict__ gatep)
{
    int idx = blockIdx.x * 256 + threadIdx.x;
    if (idx >= nrows * COUT) return;
    int n = idx / COUT, j = idx - n * COUT;
    const float* ip = in + (size_t)n * CIN;
    float acc = 0.f;
    for (int c = 0; c < CIN; ++c) {
        float xv = ip[c];
        if (AIN == 1) xv = gelu_f(xv);
        acc += xv * W[(size_t)c * COUT + j];
    }
    float v = acc + bias[j];
    if (AOUT == 1) v = fmaxf(v, 0.f);
    size_t o = (size_t)n * COUT + j;
    if (AOUT == 2) {
        float g = 1.0f / (1.0f + expf(-gatep[0]));
        v = g * v + (1.0f - g) * out[o];
    }
    out[o] = v;
}

// ------- fuse arel into qW: qWA[c, h*16+d] = sum_e qW[c, h*16+e]*arel[h,d,e] --------
__global__ __launch_bounds__(256) void fuse_kernel(
    const float* __restrict__ qW, const float* __restrict__ qb,
    const float* __restrict__ arel, float* __restrict__ qWA, float* __restrict__ qbA)
{
    __shared__ float Al[2048];
    int tid = threadIdx.x;
    for (int i = tid; i < 2048; i += 256) Al[i] = arel[i];
    __syncthreads();
    int idx = blockIdx.x * 256 + tid;      // 64 blocks * 256 = 16384 entries
    int c = idx >> 7, col = idx & 127;
    int h = col >> 4, d = col & 15;
    const float* Ah = &Al[h * 256 + d * 16];
    const float* qr = &qW[(size_t)c * 128 + h * 16];
    float acc = 0.f;
#pragma unroll
    for (int e = 0; e < 16; ++e) acc += qr[e] * Ah[e];
    qWA[idx] = acc;
    if (blockIdx.x == 0 && tid < 128) {
        int h2 = tid >> 4, d2 = tid & 15;
        const float* Ah2 = &Al[h2 * 256 + d2 * 16];
        const float* qb2 = &qb[h2 * 16];
        float accb = 0.f;
#pragma unroll
        for (int e = 0; e < 16; ++e) accb += qb2[e] * Ah2[e];
        qbA[tid] = accb;
    }
}

// ---------------- CSR-gather attention: one wave per destination node ----------------
// lane owns channels {2*lane, 2*lane+1}; h = lane>>3; 8-lane groups reduce head dots.
// Single pass: exp-sum + weighted raw-v accumulation; mrel applied post-aggregation.
__global__ __launch_bounds__(256) void gather_kernel(
    const float* __restrict__ qq, const float* __restrict__ kb,
    const float* __restrict__ vb, const int* __restrict__ off,
    const int* __restrict__ csrc, const float* __restrict__ prel,
    const float* __restrict__ mrel, float* __restrict__ agg, int N)
{
    __shared__ float M[2048];   // mrel [h][d][e]
    int tid = threadIdx.x;
    for (int i = tid; i < 2048; i += 256) M[i] = mrel[i];
    __syncthreads();
    int lane = tid & 63, wid = tid >> 6;
    int h = lane >> 3, dp = lane & 7;
    int dst = blockIdx.x * 4 + wid;
    if (dst >= N) return;

    float prl = prel[h] * 0.25f;   // * 1/sqrt(D)
    const float2 qv = *(const float2*)&qq[(size_t)dst * 128 + lane * 2];
    int beg = off[dst], end = off[dst + 1];
    float acc0 = 0.f, acc1 = 0.f, ssum = 0.f;
    int src_next = (beg < end) ? csrc[beg] : 0;
    for (int e = beg; e < end; ++e) {
        int src = src_next;
        if (e + 1 < end) src_next = csrc[e + 1];
        const float2 kv = *(const float2*)&kb[(size_t)src * 128 + lane * 2];
        float p = qv.x * kv.x + qv.y * kv.y;
        p += __shfl_xor(p, 1);
        p += __shfl_xor(p, 2);
        p += __shfl_xor(p, 4);   // 8-lane head reduction
        float sarg = fminf(fmaxf(p * prl, -60.f), 60.f);
        float ex = expf(sarg);
        ssum += ex;
        const float2 vv = *(const float2*)&vb[(size_t)src * 128 + lane * 2];
        acc0 += ex * vv.x;
        acc1 += ex * vv.y;
    }
    float inv = 1.0f / (ssum + 1e-16f);
    acc0 *= inv; acc1 *= inv;

    // post-aggregation mrel: out[h][e] = sum_d t[h][d]*M[h][d][e]
    float o0 = 0.f, o1 = 0.f;
    const float* Mh = &M[h * 256];
#pragma unroll
    for (int dd = 0; dd < 8; ++dd) {
        float b0 = __shfl(acc0, (h << 3) | dd);   // t[h][2dd]
        float b1 = __shfl(acc1, (h << 3) | dd);   // t[h][2dd+1]
        const float2 m0 = *(const float2*)&Mh[(2 * dd) * 16 + dp * 2];
        const float2 m1 = *(const float2*)&Mh[(2 * dd + 1) * 16 + dp * 2];
        o0 += b0 * m0.x + b1 * m1.x;
        o1 += b0 * m0.y + b1 * m1.y;
    }
    float* ap = &agg[(size_t)dst * 128 + lane * 2];
    ap[0] += o0;
    ap[1] += o1;
}

// ---------------- CSR build --------------------------------------------------------
__global__ void hist_kernel(const int* __restrict__ dst, int* __restrict__ deg, int E) {
    int i = blockIdx.x * 256 + threadIdx.x;
    if (i < E) atomicAdd(&deg[dst[i]], 1);
}
__global__ __launch_bounds__(1024) void scan_kernel(
    const int* __restrict__ deg, int* __restrict__ off, int N)
{
    __shared__ int s[1024];
    int tid = threadIdx.x;
    int C = (N + 1023) >> 10;
    int b = tid * C;
    int sum = 0;
    for (int i = 0; i < C; ++i) { int idx = b + i; if (idx < N) sum += deg[idx]; }
    s[tid] = sum;
    __syncthreads();
    for (int d = 1; d < 1024; d <<= 1) {
        int t = (tid >= d) ? s[tid - d] : 0;
        __syncthreads();
        s[tid] += t;
        __syncthreads();
    }
    int run = s[tid] - sum;   // exclusive prefix of this chunk
    for (int i = 0; i < C; ++i) {
        int idx = b + i;
        if (idx < N) { off[idx] = run; run += deg[idx]; }
    }
    if (tid == 1023) off[N] = s[1023];
}
__global__ void scatter_kernel(const int* __restrict__ src, const int* __restrict__ dst,
                               const int* __restrict__ off, int* __restrict__ cnt,
                               int* __restrict__ csrc, int E)
{
    int i = blockIdx.x * 256 + threadIdx.x;
    if (i < E) {
        int d = dst[i];
        int pos = off[d] + atomicAdd(&cnt[d], 1);
        csrc[pos] = src[i];
    }
}

// ---------------- L2 normalize: one wave per row, f32 -> f32 ------------------------
__global__ __launch_bounds__(256) void nnorm(
    const float* __restrict__ h0, float* __restrict__ emb, int N)
{
    int lane = threadIdx.x & 63, wid = threadIdx.x >> 6;
    int n = blockIdx.x * 4 + wid;
    if (n >= N) return;
    const float2 v = *(const float2*)&h0[(size_t)n * 128 + lane * 2];
    float s = v.x * v.x + v.y * v.y;
#pragma unroll
    for (int m = 1; m < 64; m <<= 1) s += __shfl_xor(s, m);
    float sc = 1.0f / fmaxf(sqrtf(s), 1e-12f);
    if (!isfinite(sc)) sc = 0.f;
    float2* op = (float2*)&emb[(size_t)n * 128 + lane * 2];
    *op = make_float2(v.x * sc, v.y * sc);
}

// ---------------- sentinel (f32) ----------------------------------------------------
__global__ void sentinel_kernel(float* out, int n, float val) {
    int i = blockIdx.x * 256 + threadIdx.x;
    if (i < n) out[i] = val;
}

extern "C" void kernel_launch(void* const* d_in, const int* in_sizes, int n_in,
                              void* d_out, int out_size, void* d_ws, size_t ws_size,
                              hipStream_t stream)
{
    const int N = in_sizes[0] / (TTYPES * INC);
    const int E = in_sizes[19] / 2;
    const size_t NH = (size_t)N * HID;

    const size_t need = 6 * NH * 4;   // 153.6 MB (proven available)
    if (ws_size < need) {
        sentinel_kernel<<<(out_size + 255) / 256, 256, 0, stream>>>(
            (float*)d_out, out_size, 30.0f);
        return;
    }

    const float* x     = (const float*)d_in[0];
    const float* encW  = (const float*)d_in[1];
    const float* encb  = (const float*)d_in[2];
    const float* kW    = (const float*)d_in[3];
    const float* kb_   = (const float*)d_in[4];
    const float* qW    = (const float*)d_in[5];
    const float* qb    = (const float*)d_in[6];
    const float* vW    = (const float*)d_in[7];
    const float* vb_   = (const float*)d_in[8];
    const float* aW    = (const float*)d_in[9];
    const float* ab    = (const float*)d_in[10];
    const float* skipw = (const float*)d_in[11];
    const float* arel  = (const float*)d_in[12];
    const float* mrel  = (const float*)d_in[13];
    const float* prel  = (const float*)d_in[14];
    const float* dW1   = (const float*)d_in[15];
    const float* db1   = (const float*)d_in[16];
    const float* dW2   = (const float*)d_in[17];
    const float* db2   = (const float*)d_in[18];

    // ---- ws layout (f32): hbuf[2NH] | kbuf | vbuf | qqb | agg0 = 6NH ----
    float* hbuf = (float*)d_ws;
    float* kbuf = hbuf + 2 * NH;
    float* vbuf = kbuf + NH;
    float* qqb  = vbuf + NH;
    float* agg0 = qqb + NH;

    // ---- d_out scratch ----
    // emb region [0,NH): agg1 (dead before nnorm)
    // rec region [NH, NH+N*256): CSR + qWA/qbA (dead before final decoder GEMM)
    float* agg1 = (float*)d_out;
    int*   ip   = (int*)((float*)d_out + NH);
    int* deg = ip;            ip += N;
    int* cnt = ip;            ip += N;
    int* offs[4];  for (int e = 0; e < 4; ++e) { offs[e] = ip; ip += N + 1; }
    int* csrcs[4]; for (int e = 0; e < 4; ++e) { csrcs[e] = ip; ip += E; }
    float* qWA = (float*)ip;
    float* qbA = qWA + HID * HID;

    static const int st_[4] = {0, 1, 0, 1};
    static const int dt_[4] = {1, 0, 0, 1};
    float* aggs[2] = {agg0, agg1};

    const int egrid = (E + 255) / 256;
    const int G128  = (N * 128 + 255) / 256;
    const int G256  = (N * 256 + 255) / 256;
    const int GW    = (N + 3) / 4;

    // ---- CSR build (once, reused by both layers) ----
    for (int et = 0; et < 4; ++et) {
        const int* ei = (const int*)d_in[19 + et];
        hipMemsetAsync(deg, 0, (size_t)N * 4, stream);
        hist_kernel<<<egrid, 256, 0, stream>>>(ei + E, deg, E);
        scan_kernel<<<1, 1024, 0, stream>>>(deg, offs[et], N);
        hipMemsetAsync(cnt, 0, (size_t)N * 4, stream);
        scatter_kernel<<<egrid, 256, 0, stream>>>(ei, ei + E, offs[et], cnt,
                                                  csrcs[et], E);
    }

    // ---- encoder: h[t] = relu(x[t] @ encW[t] + encb[t]) ----
    for (int t = 0; t < TTYPES; ++t) {
        ngemm<INC, HID, 0, 1><<<G128, 256, 0, stream>>>(
            x + (size_t)t * N * INC, encW + (size_t)t * INC * HID, encb + t * HID,
            hbuf + t * NH, N, nullptr);
    }

    for (int l = 0; l < 2; ++l) {
        hipMemsetAsync(agg0, 0, NH * 4, stream);
        hipMemsetAsync(agg1, 0, NH * 4, stream);
        // group by SOURCE type: k/v computed once per st; all reads pre-update
        for (int st = 0; st < TTYPES; ++st) {
            int bs = l * 2 + st;
            ngemm<HID, HID, 0, 0><<<G128, 256, 0, stream>>>(
                hbuf + st * NH, kW + (size_t)bs * HID * HID, kb_ + (size_t)bs * HID,
                kbuf, N, nullptr);
            ngemm<HID, HID, 0, 0><<<G128, 256, 0, stream>>>(
                hbuf + st * NH, vW + (size_t)bs * HID * HID, vb_ + (size_t)bs * HID,
                vbuf, N, nullptr);
            for (int et = 0; et < 4; ++et) {
                if (st_[et] != st) continue;
                int dt = dt_[et];
                int rel = l * 4 + et;
                int bd  = l * 2 + dt;
                fuse_kernel<<<64, 256, 0, stream>>>(
                    qW + (size_t)bd * HID * HID, qb + (size_t)bd * HID,
                    arel + (size_t)rel * 2048, qWA, qbA);
                ngemm<HID, HID, 0, 0><<<G128, 256, 0, stream>>>(
                    hbuf + dt * NH, qWA, qbA, qqb, N, nullptr);
                gather_kernel<<<GW, 256, 0, stream>>>(
                    qqb, kbuf, vbuf, offs[et], csrcs[et],
                    prel + (size_t)rel * HH, mrel + (size_t)rel * 2048,
                    aggs[dt], N);
            }
        }
        // h[t] = g*(gelu(agg[t]) @ aW + ab) + (1-g)*h[t]
        for (int t = 0; t < TTYPES; ++t) {
            int b = l * 2 + t;
            ngemm<HID, HID, 1, 2><<<G128, 256, 0, stream>>>(
                aggs[t], aW + (size_t)b * HID * HID, ab + (size_t)b * HID,
                hbuf + t * NH, N, skipw + b);
        }
    }

    float* emb = (float*)d_out;           // [N][128] f32
    float* rec = emb + NH;                // [N][256] f32
    nnorm<<<GW, 256, 0, stream>>>(hbuf, emb, N);
    ngemm<HID, HID, 0, 1><<<G128, 256, 0, stream>>>(
        hbuf, dW1, db1, agg0, N, nullptr);
    ngemm<HID, INC, 0, 0><<<G256, 256, 0, stream>>>(
        agg0, dW2, db2, rec, N, nullptr);
}

// Round 13
// 2625.433 us; speedup vs baseline: 21.1827x; 2.8547x over previous
//
#include <hip/hip_runtime.h>
#include <hip/hip_bf16.h>

// HGT forward, MI355X — ROUND 13: tiled GEMM (64x64 LDS tile, 4x4 microtile)
// replaces naive ngemm. CSR-gather attention, folded arel, post-agg mrel,
// pure f32, f32 outputs. ws = 153.6 MB. d_out scratch: agg1 in emb region,
// CSR + qWA in rec region (dead until final decoder GEMM).

#define HH 8
#define HID 128
#define INC 256
#define TTYPES 2

typedef unsigned int u32;

__device__ __forceinline__ float gelu_f(float x) {
    return 0.5f * x * (1.0f + erff(x * 0.7071067811865476f));
}

// ---------------- Tiled GEMM: out[n,j] = act(sum_c act_in(in[n,c])*W[c,j] + b[j]) ----
// 64x64 block tile, 4x4 per-thread microtile, W chunk + transposed rows in LDS.
// AIN: 0 none, 1 gelu. AOUT: 0 none, 1 relu, 2 skip blend out = g*v + (1-g)*out_old.
template <int CIN, int COUT, int AIN, int AOUT>
__global__ __launch_bounds__(256) void gemm_kernel(
    const float* __restrict__ in, const float* __restrict__ W,
    const float* __restrict__ bias, float* __restrict__ out, int nrows,
    const float* __restrict__ gatep)
{
    __shared__ __align__(16) float Wl[64 * 64];   // current K-chunk of W
    __shared__ __align__(16) float Rt[64 * 66];   // transposed row chunk
    const int tid = threadIdx.x;
    const int rowbase = blockIdx.x * 64;
    const int colbase = blockIdx.y * 64;

    const int tcol = tid & 15;
    const int trow = tid >> 4;
    const int col0 = tcol * 4;
    const int row0 = trow * 4;
    float acc[4][4] = {};

    for (int kc = 0; kc < CIN; kc += 64) {
        __syncthreads();
        for (int i = tid; i < 64 * 16; i += 256) {   // W chunk [64][64]
            int r = i >> 4, j4 = i & 15;
            ((float4*)Wl)[r * 16 + j4] =
                *(const float4*)&W[(size_t)(kc + r) * COUT + colbase + j4 * 4];
        }
        for (int i = tid; i < 64 * 16; i += 256) {   // rows, transposed
            int r = i >> 4, c4 = i & 15;
            int gr = rowbase + r;
            float4 v4 = make_float4(0.f, 0.f, 0.f, 0.f);
            if (gr < nrows) v4 = *(const float4*)&in[(size_t)gr * CIN + kc + c4 * 4];
            if (AIN == 1) {
                v4.x = gelu_f(v4.x); v4.y = gelu_f(v4.y);
                v4.z = gelu_f(v4.z); v4.w = gelu_f(v4.w);
            }
            int cc = c4 * 4;
            Rt[(cc + 0) * 66 + r] = v4.x;
            Rt[(cc + 1) * 66 + r] = v4.y;
            Rt[(cc + 2) * 66 + r] = v4.z;
            Rt[(cc + 3) * 66 + r] = v4.w;
        }
        __syncthreads();
#pragma unroll 8
        for (int c = 0; c < 64; ++c) {
            const float2 ra = *(const float2*)&Rt[c * 66 + row0];
            const float2 rb = *(const float2*)&Rt[c * 66 + row0 + 2];
            const float4 wv = *(const float4*)&Wl[c * 64 + col0];
            acc[0][0] += ra.x * wv.x; acc[0][1] += ra.x * wv.y;
            acc[0][2] += ra.x * wv.z; acc[0][3] += ra.x * wv.w;
            acc[1][0] += ra.y * wv.x; acc[1][1] += ra.y * wv.y;
            acc[1][2] += ra.y * wv.z; acc[1][3] += ra.y * wv.w;
            acc[2][0] += rb.x * wv.x; acc[2][1] += rb.x * wv.y;
            acc[2][2] += rb.x * wv.z; acc[2][3] += rb.x * wv.w;
            acc[3][0] += rb.y * wv.x; acc[3][1] += rb.y * wv.y;
            acc[3][2] += rb.y * wv.z; acc[3][3] += rb.y * wv.w;
        }
    }

    float bv[4];
#pragma unroll
    for (int j = 0; j < 4; ++j) bv[j] = bias[colbase + col0 + j];
    float g = 0.f;
    if (AOUT == 2) g = 1.0f / (1.0f + expf(-gatep[0]));
#pragma unroll
    for (int r = 0; r < 4; ++r) {
        int gr = rowbase + row0 + r;
        if (gr >= nrows) continue;
        size_t base = (size_t)gr * COUT + colbase + col0;
#pragma unroll
        for (int j = 0; j < 4; ++j) {
            float v = acc[r][j] + bv[j];
            if (AOUT == 1) v = fmaxf(v, 0.f);
            if (AOUT == 2) v = g * v + (1.0f - g) * out[base + j];
            out[base + j] = v;
        }
    }
}

// ------- fuse arel into qW: qWA[c, h*16+d] = sum_e qW[c, h*16+e]*arel[h,d,e] --------
__global__ __launch_bounds__(256) void fuse_kernel(
    const float* __restrict__ qW, const float* __restrict__ qb,
    const float* __restrict__ arel, float* __restrict__ qWA, float* __restrict__ qbA)
{
    __shared__ float Al[2048];
    int tid = threadIdx.x;
    for (int i = tid; i < 2048; i += 256) Al[i] = arel[i];
    __syncthreads();
    int idx = blockIdx.x * 256 + tid;      // 64 blocks * 256 = 16384 entries
    int c = idx >> 7, col = idx & 127;
    int h = col >> 4, d = col & 15;
    const float* Ah = &Al[h * 256 + d * 16];
    const float* qr = &qW[(size_t)c * 128 + h * 16];
    float acc = 0.f;
#pragma unroll
    for (int e = 0; e < 16; ++e) acc += qr[e] * Ah[e];
    qWA[idx] = acc;
    if (blockIdx.x == 0 && tid < 128) {
        int h2 = tid >> 4, d2 = tid & 15;
        const float* Ah2 = &Al[h2 * 256 + d2 * 16];
        const float* qb2 = &qb[h2 * 16];
        float accb = 0.f;
#pragma unroll
        for (int e = 0; e < 16; ++e) accb += qb2[e] * Ah2[e];
        qbA[tid] = accb;
    }
}

// ---------------- CSR-gather attention: one wave per destination node ----------------
__global__ __launch_bounds__(256) void gather_kernel(
    const float* __restrict__ qq, const float* __restrict__ kb,
    const float* __restrict__ vb, const int* __restrict__ off,
    const int* __restrict__ csrc, const float* __restrict__ prel,
    const float* __restrict__ mrel, float* __restrict__ agg, int N)
{
    __shared__ float M[2048];   // mrel [h][d][e]
    int tid = threadIdx.x;
    for (int i = tid; i < 2048; i += 256) M[i] = mrel[i];
    __syncthreads();
    int lane = tid & 63, wid = tid >> 6;
    int h = lane >> 3, dp = lane & 7;
    int dst = blockIdx.x * 4 + wid;
    if (dst >= N) return;

    float prl = prel[h] * 0.25f;   // * 1/sqrt(D)
    const float2 qv = *(const float2*)&qq[(size_t)dst * 128 + lane * 2];
    int beg = off[dst], end = off[dst + 1];
    float acc0 = 0.f, acc1 = 0.f, ssum = 0.f;
    int src_next = (beg < end) ? csrc[beg] : 0;
    for (int e = beg; e < end; ++e) {
        int src = src_next;
        if (e + 1 < end) src_next = csrc[e + 1];
        const float2 kv = *(const float2*)&kb[(size_t)src * 128 + lane * 2];
        float p = qv.x * kv.x + qv.y * kv.y;
        p += __shfl_xor(p, 1);
        p += __shfl_xor(p, 2);
        p += __shfl_xor(p, 4);   // 8-lane head reduction
        float sarg = fminf(fmaxf(p * prl, -60.f), 60.f);
        float ex = expf(sarg);
        ssum += ex;
        const float2 vv = *(const float2*)&vb[(size_t)src * 128 + lane * 2];
        acc0 += ex * vv.x;
        acc1 += ex * vv.y;
    }
    float inv = 1.0f / (ssum + 1e-16f);
    acc0 *= inv; acc1 *= inv;

    // post-aggregation mrel: out[h][e] = sum_d t[h][d]*M[h][d][e]
    float o0 = 0.f, o1 = 0.f;
    const float* Mh = &M[h * 256];
#pragma unroll
    for (int dd = 0; dd < 8; ++dd) {
        float b0 = __shfl(acc0, (h << 3) | dd);   // t[h][2dd]
        float b1 = __shfl(acc1, (h << 3) | dd);   // t[h][2dd+1]
        const float2 m0 = *(const float2*)&Mh[(2 * dd) * 16 + dp * 2];
        const float2 m1 = *(const float2*)&Mh[(2 * dd + 1) * 16 + dp * 2];
        o0 += b0 * m0.x + b1 * m1.x;
        o1 += b0 * m0.y + b1 * m1.y;
    }
    float* ap = &agg[(size_t)dst * 128 + lane * 2];
    ap[0] += o0;
    ap[1] += o1;
}

// ---------------- CSR build --------------------------------------------------------
__global__ void hist_kernel(const int* __restrict__ dst, int* __restrict__ deg, int E) {
    int i = blockIdx.x * 256 + threadIdx.x;
    if (i < E) atomicAdd(&deg[dst[i]], 1);
}
__global__ __launch_bounds__(1024) void scan_kernel(
    const int* __restrict__ deg, int* __restrict__ off, int N)
{
    __shared__ int s[1024];
    int tid = threadIdx.x;
    int C = (N + 1023) >> 10;
    int b = tid * C;
    int sum = 0;
    for (int i = 0; i < C; ++i) { int idx = b + i; if (idx < N) sum += deg[idx]; }
    s[tid] = sum;
    __syncthreads();
    for (int d = 1; d < 1024; d <<= 1) {
        int t = (tid >= d) ? s[tid - d] : 0;
        __syncthreads();
        s[tid] += t;
        __syncthreads();
    }
    int run = s[tid] - sum;   // exclusive prefix of this chunk
    for (int i = 0; i < C; ++i) {
        int idx = b + i;
        if (idx < N) { off[idx] = run; run += deg[idx]; }
    }
    if (tid == 1023) off[N] = s[1023];
}
__global__ void scatter_kernel(const int* __restrict__ src, const int* __restrict__ dst,
                               const int* __restrict__ off, int* __restrict__ cnt,
                               int* __restrict__ csrc, int E)
{
    int i = blockIdx.x * 256 + threadIdx.x;
    if (i < E) {
        int d = dst[i];
        int pos = off[d] + atomicAdd(&cnt[d], 1);
        csrc[pos] = src[i];
    }
}

// ---------------- L2 normalize: one wave per row, f32 -> f32 ------------------------
__global__ __launch_bounds__(256) void nnorm(
    const float* __restrict__ h0, float* __restrict__ emb, int N)
{
    int lane = threadIdx.x & 63, wid = threadIdx.x >> 6;
    int n = blockIdx.x * 4 + wid;
    if (n >= N) return;
    const float2 v = *(const float2*)&h0[(size_t)n * 128 + lane * 2];
    float s = v.x * v.x + v.y * v.y;
#pragma unroll
    for (int m = 1; m < 64; m <<= 1) s += __shfl_xor(s, m);
    float sc = 1.0f / fmaxf(sqrtf(s), 1e-12f);
    if (!isfinite(sc)) sc = 0.f;
    float2* op = (float2*)&emb[(size_t)n * 128 + lane * 2];
    *op = make_float2(v.x * sc, v.y * sc);
}

// ---------------- sentinel (f32) ----------------------------------------------------
__global__ void sentinel_kernel(float* out, int n, float val) {
    int i = blockIdx.x * 256 + threadIdx.x;
    if (i < n) out[i] = val;
}

extern "C" void kernel_launch(void* const* d_in, const int* in_sizes, int n_in,
                              void* d_out, int out_size, void* d_ws, size_t ws_size,
                              hipStream_t stream)
{
    const int N = in_sizes[0] / (TTYPES * INC);
    const int E = in_sizes[19] / 2;
    const size_t NH = (size_t)N * HID;

    const size_t need = 6 * NH * 4;   // 153.6 MB (proven available)
    if (ws_size < need) {
        sentinel_kernel<<<(out_size + 255) / 256, 256, 0, stream>>>(
            (float*)d_out, out_size, 30.0f);
        return;
    }

    const float* x     = (const float*)d_in[0];
    const float* encW  = (const float*)d_in[1];
    const float* encb  = (const float*)d_in[2];
    const float* kW    = (const float*)d_in[3];
    const float* kb_   = (const float*)d_in[4];
    const float* qW    = (const float*)d_in[5];
    const float* qb    = (const float*)d_in[6];
    const float* vW    = (const float*)d_in[7];
    const float* vb_   = (const float*)d_in[8];
    const float* aW    = (const float*)d_in[9];
    const float* ab    = (const float*)d_in[10];
    const float* skipw = (const float*)d_in[11];
    const float* arel  = (const float*)d_in[12];
    const float* mrel  = (const float*)d_in[13];
    const float* prel  = (const float*)d_in[14];
    const float* dW1   = (const float*)d_in[15];
    const float* db1   = (const float*)d_in[16];
    const float* dW2   = (const float*)d_in[17];
    const float* db2   = (const float*)d_in[18];

    // ---- ws layout (f32): hbuf[2NH] | kbuf | vbuf | qqb | agg0 = 6NH ----
    float* hbuf = (float*)d_ws;
    float* kbuf = hbuf + 2 * NH;
    float* vbuf = kbuf + NH;
    float* qqb  = vbuf + NH;
    float* agg0 = qqb + NH;

    // ---- d_out scratch ----
    float* agg1 = (float*)d_out;                 // emb region, dead before nnorm
    int*   ip   = (int*)((float*)d_out + NH);    // rec region
    int* deg = ip;            ip += N;
    int* cnt = ip;            ip += N;
    int* offs[4];  for (int e = 0; e < 4; ++e) { offs[e] = ip; ip += N + 1; }
    int* csrcs[4]; for (int e = 0; e < 4; ++e) { csrcs[e] = ip; ip += E; }
    float* qWA = (float*)ip;
    float* qbA = qWA + HID * HID;

    static const int st_[4] = {0, 1, 0, 1};
    static const int dt_[4] = {1, 0, 0, 1};
    float* aggs[2] = {agg0, agg1};

    const int egrid = (E + 255) / 256;
    const int RT    = (N + 63) / 64;
    const int GW    = (N + 3) / 4;

    // ---- CSR build (once, reused by both layers) ----
    for (int et = 0; et < 4; ++et) {
        const int* ei = (const int*)d_in[19 + et];
        hipMemsetAsync(deg, 0, (size_t)N * 4, stream);
        hist_kernel<<<egrid, 256, 0, stream>>>(ei + E, deg, E);
        scan_kernel<<<1, 1024, 0, stream>>>(deg, offs[et], N);
        hipMemsetAsync(cnt, 0, (size_t)N * 4, stream);
        scatter_kernel<<<egrid, 256, 0, stream>>>(ei, ei + E, offs[et], cnt,
                                                  csrcs[et], E);
    }

    // ---- encoder: h[t] = relu(x[t] @ encW[t] + encb[t]) ----
    for (int t = 0; t < TTYPES; ++t) {
        gemm_kernel<INC, HID, 0, 1><<<dim3(RT, 2), 256, 0, stream>>>(
            x + (size_t)t * N * INC, encW + (size_t)t * INC * HID, encb + t * HID,
            hbuf + t * NH, N, nullptr);
    }

    for (int l = 0; l < 2; ++l) {
        hipMemsetAsync(agg0, 0, NH * 4, stream);
        hipMemsetAsync(agg1, 0, NH * 4, stream);
        // group by SOURCE type: k/v computed once per st; all reads pre-update
        for (int st = 0; st < TTYPES; ++st) {
            int bs = l * 2 + st;
            gemm_kernel<HID, HID, 0, 0><<<dim3(RT, 2), 256, 0, stream>>>(
                hbuf + st * NH, kW + (size_t)bs * HID * HID, kb_ + (size_t)bs * HID,
                kbuf, N, nullptr);
            gemm_kernel<HID, HID, 0, 0><<<dim3(RT, 2), 256, 0, stream>>>(
                hbuf + st * NH, vW + (size_t)bs * HID * HID, vb_ + (size_t)bs * HID,
                vbuf, N, nullptr);
            for (int et = 0; et < 4; ++et) {
                if (st_[et] != st) continue;
                int dt = dt_[et];
                int rel = l * 4 + et;
                int bd  = l * 2 + dt;
                fuse_kernel<<<64, 256, 0, stream>>>(
                    qW + (size_t)bd * HID * HID, qb + (size_t)bd * HID,
                    arel + (size_t)rel * 2048, qWA, qbA);
                gemm_kernel<HID, HID, 0, 0><<<dim3(RT, 2), 256, 0, stream>>>(
                    hbuf + dt * NH, qWA, qbA, qqb, N, nullptr);
                gather_kernel<<<GW, 256, 0, stream>>>(
                    qqb, kbuf, vbuf, offs[et], csrcs[et],
                    prel + (size_t)rel * HH, mrel + (size_t)rel * 2048,
                    aggs[dt], N);
            }
        }
        // h[t] = g*(gelu(agg[t]) @ aW + ab) + (1-g)*h[t]
        for (int t = 0; t < TTYPES; ++t) {
            int b = l * 2 + t;
            gemm_kernel<HID, HID, 1, 2><<<dim3(RT, 2), 256, 0, stream>>>(
                aggs[t], aW + (size_t)b * HID * HID, ab + (size_t)b * HID,
                hbuf + t * NH, N, skipw + b);
        }
    }

    float* emb = (float*)d_out;           // [N][128] f32
    float* rec = emb + NH;                // [N][256] f32
    nnorm<<<GW, 256, 0, stream>>>(hbuf, emb, N);
    gemm_kernel<HID, HID, 0, 1><<<dim3(RT, 2), 256, 0, stream>>>(
        hbuf, dW1, db1, agg0, N, nullptr);
    gemm_kernel<HID, INC, 0, 0><<<dim3(RT, 4), 256, 0, stream>>>(
        agg0, dW2, db2, rec, N, nullptr);
}